// Round 8
// baseline (109.631 us; speedup 1.0000x reference)
//
#include <hip/hip_runtime.h>

typedef unsigned int uint;
typedef unsigned short ushort_t;
typedef __attribute__((ext_vector_type(8))) short short8v;   // 8 bf16 (4 VGPRs)
typedef __attribute__((ext_vector_type(4))) float f32x4;

#define BATCH 8
#define HH 128
#define WW 128
#define CC 64
#define NPIX (BATCH * HH * WW)   // 131072
#define KK 9
#define BN_EPS 1e-3f

__device__ __forceinline__ uint f2bfbits(float f) {
    uint u = __float_as_uint(f);
    return (u + 0x7fffu + ((u >> 16) & 1u)) >> 16;   // RNE
}

// ---- setup: w1 -> bf16 transposed [d][c]; pad w2 to 12; fold b1+BN ----
__global__ void setup_kernel(const float* __restrict__ w1,
                             const float* __restrict__ b1,
                             const float* __restrict__ gamma,
                             const float* __restrict__ beta,
                             const float* __restrict__ bn_mean,
                             const float* __restrict__ bn_var,
                             const float* __restrict__ w2,
                             const float* __restrict__ b2,
                             ushort_t* __restrict__ w1b,   // [64][64] bf16: w1b[d][c] = w1[c][d]
                             float* __restrict__ w2p,      // [64][12] padded
                             float* __restrict__ scalef,   // [64]
                             float* __restrict__ biasf,    // [64]
                             float* __restrict__ b2f)      // [9]
{
    int t = blockIdx.x * blockDim.x + threadIdx.x;
    int nt = gridDim.x * blockDim.x;
    for (int idx = t; idx < CC * CC; idx += nt) {
        int d = idx >> 6, c = idx & 63;
        w1b[idx] = (ushort_t)f2bfbits(w1[c * CC + d]);
    }
    for (int idx = t; idx < CC * 12; idx += nt) {
        int d = idx / 12, k = idx - d * 12;
        w2p[idx] = (k < KK) ? w2[d * KK + k] : 0.f;
    }
    if (t < CC) {
        float s = gamma[t] * rsqrtf(bn_var[t] + BN_EPS);
        scalef[t] = s;
        biasf[t] = (b1[t] - bn_mean[t]) * s + beta[t];
    }
    if (t < KK) b2f[t] = b2[t];
}

// ---- K1: kern generation. stage -> MFMA GEMM1 -> VALU GEMM2 ----
__global__ __launch_bounds__(256) void kern_gen(
    const float* __restrict__ x,
    const ushort_t* __restrict__ w1b,
    const float* __restrict__ w2p,
    const float* __restrict__ scalef,
    const float* __restrict__ biasf,
    const float* __restrict__ b2f,
    float* __restrict__ kout)    // [NPIX][9]
{
    __shared__ __align__(16) unsigned char smem[26880];
    ushort_t* xB = (ushort_t*)smem;              // [64][72] bf16 (pad -> conflict-free b128)
    float*    hS = (float*)(smem + 9216);        // [64][69] f32

    const int t = threadIdx.x;
    int bid = blockIdx.x;
    bid = (bid & 7) * 256 + (bid >> 3);          // XCD slab swizzle (2048 = 8*256, bijective)
    const int p0 = bid * 64;

    // ---- phase 0: coalesced stage x -> bf16 LDS ----
#pragma unroll
    for (int r = 0; r < 4; ++r) {
        int idx = t + r * 256;
        int px = idx >> 4, c4 = idx & 15;
        float4 v = *(const float4*)(x + (size_t)(p0 + px) * CC + c4 * 4);
        uint2 pk;
        pk.x = f2bfbits(v.x) | (f2bfbits(v.y) << 16);
        pk.y = f2bfbits(v.z) | (f2bfbits(v.w) << 16);
        *(uint2*)(xB + px * 72 + c4 * 4) = pk;
    }
    __syncthreads();

    // ---- phase 1: GEMM1 h = relu(bn(x @ w1)) via MFMA; wave w = d-strip ----
    {
        const int l = t & 63;
        const int w = __builtin_amdgcn_readfirstlane(t >> 6);
        const int lr = l & 15, lq = l >> 4;

        f32x4 acc[4];
#pragma unroll
        for (int m = 0; m < 4; ++m) acc[m] = (f32x4){0.f, 0.f, 0.f, 0.f};

#pragma unroll
        for (int ks = 0; ks < 2; ++ks) {
            short8v bfrag = *(const short8v*)(w1b + (w * 16 + lr) * CC + ks * 32 + lq * 8);
#pragma unroll
            for (int m = 0; m < 4; ++m) {
                short8v afrag = *(const short8v*)(xB + (m * 16 + lr) * 72 + ks * 32 + lq * 8);
                acc[m] = __builtin_amdgcn_mfma_f32_16x16x32_bf16(afrag, bfrag, acc[m], 0, 0, 0);
            }
        }
        // C layout: col = lr (= d offset), row = lq*4 + r (= px offset)
        const int d = w * 16 + lr;
        const float s = scalef[d], bb = biasf[d];
#pragma unroll
        for (int m = 0; m < 4; ++m)
#pragma unroll
            for (int r = 0; r < 4; ++r)
                hS[(m * 16 + lq * 4 + r) * 69 + d] = fmaxf(fmaf(acc[m][r], s, bb), 0.f);
    }
    __syncthreads();

    // ---- phase 2: kern = h @ w2 + b2 (VALU; thread = (px, d-quarter)) ----
    {
        const int px = t >> 2, dq = t & 3;
        float kp[KK];
#pragma unroll
        for (int k = 0; k < KK; ++k) kp[k] = 0.f;

        const float* hrow = hS + px * 69 + dq * 16;
#pragma unroll
        for (int e = 0; e < 16; ++e) {
            float hv = hrow[e];
            const float4* wr = (const float4*)(w2p + (dq * 16 + e) * 12);
            float4 wa = wr[0], wb = wr[1], wc = wr[2];
            kp[0] = fmaf(hv, wa.x, kp[0]);
            kp[1] = fmaf(hv, wa.y, kp[1]);
            kp[2] = fmaf(hv, wa.z, kp[2]);
            kp[3] = fmaf(hv, wa.w, kp[3]);
            kp[4] = fmaf(hv, wb.x, kp[4]);
            kp[5] = fmaf(hv, wb.y, kp[5]);
            kp[6] = fmaf(hv, wb.z, kp[6]);
            kp[7] = fmaf(hv, wb.w, kp[7]);
            kp[8] = fmaf(hv, wc.x, kp[8]);
        }
#pragma unroll
        for (int k = 0; k < KK; ++k) {
            kp[k] += __shfl_xor(kp[k], 1, 64);
            kp[k] += __shfl_xor(kp[k], 2, 64);
        }
        if (dq == 0) {
            float* kr = kout + (size_t)(p0 + px) * KK;
#pragma unroll
            for (int k = 0; k < KK; ++k) kr[k] = kp[k] + b2f[k];
        }
    }
}

// ---- K2: involution. thread = (pixel, 16-ch quarter). LDS-free ----
__global__ __launch_bounds__(256) void invol2(
    const float* __restrict__ x,
    const float* __restrict__ kern_in,   // [NPIX][9]
    float* __restrict__ out)             // [NPIX][64]
{
    // XCD slab swizzle matching K1's slabs -> x window L2-warm per XCD
    int bid = blockIdx.x;
    bid = (bid & 7) * 256 + (bid >> 3);
    int T = bid * 256 + threadIdx.x;
    int p = T >> 2;
    int c0 = (T & 3) * 16;
    int b = p >> 14;
    int i = (p >> 7) & 127;
    int j = p & 127;

    float kern[KK];
    const float* kr = kern_in + (size_t)p * KK;
#pragma unroll
    for (int k = 0; k < KK; ++k) kern[k] = kr[k];

    float acc[16];
#pragma unroll
    for (int e = 0; e < 16; ++e) acc[e] = 0.f;

#pragma unroll
    for (int tap = 0; tap < KK; ++tap) {
        const int di = tap / 3 - 1, dj = tap % 3 - 1;
        int ii = i + di, jj = j + dj;
        bool valid = (ii >= 0) && (ii < HH) && (jj >= 0) && (jj < WW);
        float kv = valid ? kern[tap] : 0.f;
        int iic = min(max(ii, 0), HH - 1);
        int jjc = min(max(jj, 0), WW - 1);
        const float4* np = (const float4*)(x + (((size_t)b * HH + iic) * WW + jjc) * CC + c0);
#pragma unroll
        for (int f = 0; f < 4; ++f) {
            float4 v = np[f];
            acc[f * 4 + 0] = fmaf(kv, v.x, acc[f * 4 + 0]);
            acc[f * 4 + 1] = fmaf(kv, v.y, acc[f * 4 + 1]);
            acc[f * 4 + 2] = fmaf(kv, v.z, acc[f * 4 + 2]);
            acc[f * 4 + 3] = fmaf(kv, v.w, acc[f * 4 + 3]);
        }
    }

    // nontemporal stores (out is write-once; don't evict x from L2).
    // ext_vector type (f32x4), NOT HIP float4 — builtin rejects class types.
    f32x4* op = (f32x4*)(out + (size_t)p * CC + c0);
#pragma unroll
    for (int f = 0; f < 4; ++f) {
        f32x4 v = {acc[f * 4 + 0], acc[f * 4 + 1], acc[f * 4 + 2], acc[f * 4 + 3]};
        __builtin_nontemporal_store(v, &op[f]);
    }
}

extern "C" void kernel_launch(void* const* d_in, const int* in_sizes, int n_in,
                              void* d_out, int out_size, void* d_ws, size_t ws_size,
                              hipStream_t stream) {
    const float* x       = (const float*)d_in[0];
    const float* w1      = (const float*)d_in[1];
    const float* b1      = (const float*)d_in[2];
    const float* gamma   = (const float*)d_in[3];
    const float* beta    = (const float*)d_in[4];
    const float* bn_mean = (const float*)d_in[5];
    const float* bn_var  = (const float*)d_in[6];
    const float* w2      = (const float*)d_in[7];
    const float* b2      = (const float*)d_in[8];

    ushort_t* w1b = (ushort_t*)d_ws;                 // 4096 ushort = 8192 B
    float* w2p    = (float*)d_ws + 2048;             // 768
    float* scalef = w2p + CC * 12;                   // 64
    float* biasf  = scalef + CC;                     // 64
    float* b2f    = biasf + CC;                      // 9

    float* out  = (float*)d_out;
    float* kout = out + (size_t)NPIX * CC;

    hipLaunchKernelGGL(setup_kernel, dim3(20), dim3(256), 0, stream,
                       w1, b1, gamma, beta, bn_mean, bn_var, w2, b2,
                       w1b, w2p, scalef, biasf, b2f);

    hipLaunchKernelGGL(kern_gen, dim3(NPIX / 64), dim3(256), 0, stream,
                       x, w1b, w2p, scalef, biasf, b2f, kout);

    hipLaunchKernelGGL(invol2, dim3(NPIX * 4 / 256), dim3(256), 0, stream,
                       x, kout, out);
}

// Round 9
// 61.691 us; speedup vs baseline: 1.7771x; 1.7771x over previous
//
#include <hip/hip_runtime.h>

typedef unsigned int uint;
typedef unsigned short ushort_t;
typedef __attribute__((ext_vector_type(8))) short short8v;   // 8 bf16 (4 VGPRs)
typedef __attribute__((ext_vector_type(4))) float f32x4;

#define BATCH 8
#define HH 128
#define WW 128
#define CC 64
#define NPIX (BATCH * HH * WW)   // 131072
#define KK 9
#define BN_EPS 1e-3f
#define HSTR 88                   // hL row stride (bf16): 176B = 16B-aligned, ~2-way banks

__device__ __forceinline__ uint f2bfbits(float f) {
    uint u = __float_as_uint(f);
    return (u + 0x7fffu + ((u >> 16) & 1u)) >> 16;   // RNE
}

// ---- setup: w1 -> bf16 [d][c]; w2 -> bf16 transposed [k][d] (16 rows, pad 0); fold BN ----
__global__ void setup_kernel(const float* __restrict__ w1,
                             const float* __restrict__ b1,
                             const float* __restrict__ gamma,
                             const float* __restrict__ beta,
                             const float* __restrict__ bn_mean,
                             const float* __restrict__ bn_var,
                             const float* __restrict__ w2,
                             const float* __restrict__ b2,
                             ushort_t* __restrict__ w1b,    // [64][64] bf16: w1b[d][c] = w1[c][d]
                             ushort_t* __restrict__ w2bT,   // [16][64] bf16: w2bT[k][d] = w2[d][k]
                             float* __restrict__ scalef,    // [64]
                             float* __restrict__ biasf,     // [64]
                             float* __restrict__ b2f)       // [9]
{
    int t = blockIdx.x * blockDim.x + threadIdx.x;
    int nt = gridDim.x * blockDim.x;
    for (int idx = t; idx < CC * CC; idx += nt) {
        int d = idx >> 6, c = idx & 63;
        w1b[idx] = (ushort_t)f2bfbits(w1[c * CC + d]);
    }
    for (int idx = t; idx < 16 * CC; idx += nt) {
        int k = idx >> 6, d = idx & 63;
        w2bT[idx] = (k < KK) ? (ushort_t)f2bfbits(w2[d * KK + k]) : (ushort_t)0;
    }
    if (t < CC) {
        float s = gamma[t] * rsqrtf(bn_var[t] + BN_EPS);
        scalef[t] = s;
        biasf[t] = (b1[t] - bn_mean[t]) * s + beta[t];
    }
    if (t < KK) b2f[t] = b2[t];
}

// ---- fused, wave-autonomous: wave = 16 pixels, NO __syncthreads ----
__global__ __launch_bounds__(256) void invol_fused(
    const float* __restrict__ x,
    const ushort_t* __restrict__ w1b,
    const ushort_t* __restrict__ w2bT,
    const float* __restrict__ scalef,
    const float* __restrict__ biasf,
    const float* __restrict__ b2f,
    float* __restrict__ out,     // [NPIX][64]
    float* __restrict__ kout)    // [NPIX][9]
{
    __shared__ ushort_t hL[4][16][HSTR];   // per-wave h tile (bf16), 11.3 KB
    __shared__ float    kS[4][16][12];     // per-wave kern tile, 3 KB

    const int t = threadIdx.x;
    const int w = t >> 6;
    const int l = t & 63;
    const int lq = l >> 4, lr = l & 15;
    int bid = blockIdx.x;
    bid = (bid & 7) * 256 + (bid >> 3);    // XCD slab swizzle (2048 = 8*256, bijective)
    const int p0 = bid * 64 + w * 16;      // this wave's 16-pixel base

    // ---- GEMM1 A-frags: direct global load + cvt (lane = A[row=lr][k=lq*8+j]) ----
    short8v af[2];
#pragma unroll
    for (int ks = 0; ks < 2; ++ks) {
        const float4* xp = (const float4*)(x + (size_t)(p0 + lr) * CC + ks * 32 + lq * 8);
        float4 a = xp[0], b = xp[1];
        union { uint4 u; short8v s; } cv;
        cv.u.x = f2bfbits(a.x) | (f2bfbits(a.y) << 16);
        cv.u.y = f2bfbits(a.z) | (f2bfbits(a.w) << 16);
        cv.u.z = f2bfbits(b.x) | (f2bfbits(b.y) << 16);
        cv.u.w = f2bfbits(b.z) | (f2bfbits(b.w) << 16);
        af[ks] = cv.s;
    }

    // ---- GEMM1: 4 n-strips of d; h C-layout -> BN+ReLU -> bf16 -> hL ----
#pragma unroll
    for (int n = 0; n < 4; ++n) {
        f32x4 hacc = (f32x4){0.f, 0.f, 0.f, 0.f};
#pragma unroll
        for (int ks = 0; ks < 2; ++ks) {
            short8v bf = *(const short8v*)(w1b + (n * 16 + lr) * CC + ks * 32 + lq * 8);
            hacc = __builtin_amdgcn_mfma_f32_16x16x32_bf16(af[ks], bf, hacc, 0, 0, 0);
        }
        const int d = n * 16 + lr;
        const float s = scalef[d], bb = biasf[d];
#pragma unroll
        for (int r = 0; r < 4; ++r) {
            float hv = fmaxf(fmaf(hacc[r], s, bb), 0.f);
            hL[w][lq * 4 + r][d] = (ushort_t)f2bfbits(hv);   // C-layout: row=px, col=d
        }
    }
    // same-wave LDS handoff: compiler inserts lgkmcnt (r5-proven pattern)

    // ---- GEMM2: kern = h @ w2 + b2 via MFMA (M=16px, N=16 pad, K=64) ----
    f32x4 acc2 = (f32x4){0.f, 0.f, 0.f, 0.f};
#pragma unroll
    for (int ks = 0; ks < 2; ++ks) {
        short8v a2 = *(const short8v*)(&hL[w][lr][ks * 32 + lq * 8]);
        short8v b2v = *(const short8v*)(w2bT + lr * CC + ks * 32 + lq * 8);
        acc2 = __builtin_amdgcn_mfma_f32_16x16x32_bf16(a2, b2v, acc2, 0, 0, 0);
    }
    // C2: lane holds kern[px=lq*4+r][k=lr] (lr<9 valid)
    if (lr < KK) {
        const float bk = b2f[lr];
#pragma unroll
        for (int r = 0; r < 4; ++r) {
            float kv = acc2[r] + bk;
            kS[w][lq * 4 + r][lr] = kv;
            kout[(size_t)(p0 + lq * 4 + r) * KK + lr] = kv;
        }
    }
    // same-wave handoff again (lgkmcnt)

    // ---- involution: lane = (px=lr, ch-quarter=lq) ----
    float kern[KK];
#pragma unroll
    for (int k = 0; k < KK; ++k) kern[k] = kS[w][lr][k];

    const int p = p0 + lr;
    const int b = p >> 14;
    const int i = (p >> 7) & 127;           // wave-uniform (p0 multiple of 16, row=128)
    const int j = p & 127;
    const int c0 = lq * 16;

    float4 acc[4];
#pragma unroll
    for (int f = 0; f < 4; ++f) acc[f] = make_float4(0.f, 0.f, 0.f, 0.f);

#pragma unroll
    for (int ti = -1; ti <= 1; ++ti) {
        int ii = i + ti;
        if (ii < 0 || ii >= HH) continue;   // wave-uniform skip (zero-pad)
        const float* rowp = x + ((size_t)b * HH + ii) * WW * CC;
#pragma unroll
        for (int tj = -1; tj <= 1; ++tj) {
            const int tap = (ti + 1) * 3 + (tj + 1);
            int jj = j + tj;
            bool valid = (jj >= 0) && (jj < WW);
            float kv = valid ? kern[tap] : 0.f;
            int jjc = min(max(jj, 0), WW - 1);
            const float4* np = (const float4*)(rowp + jjc * CC + c0);
#pragma unroll
            for (int f = 0; f < 4; ++f) {
                float4 v = np[f];
                acc[f].x = fmaf(kv, v.x, acc[f].x);
                acc[f].y = fmaf(kv, v.y, acc[f].y);
                acc[f].z = fmaf(kv, v.z, acc[f].z);
                acc[f].w = fmaf(kv, v.w, acc[f].w);
            }
        }
    }

    float4* op = (float4*)(out + (size_t)p * CC + c0);
#pragma unroll
    for (int f = 0; f < 4; ++f) op[f] = acc[f];
}

extern "C" void kernel_launch(void* const* d_in, const int* in_sizes, int n_in,
                              void* d_out, int out_size, void* d_ws, size_t ws_size,
                              hipStream_t stream) {
    const float* x       = (const float*)d_in[0];
    const float* w1      = (const float*)d_in[1];
    const float* b1      = (const float*)d_in[2];
    const float* gamma   = (const float*)d_in[3];
    const float* beta    = (const float*)d_in[4];
    const float* bn_mean = (const float*)d_in[5];
    const float* bn_var  = (const float*)d_in[6];
    const float* w2      = (const float*)d_in[7];
    const float* b2      = (const float*)d_in[8];

    ushort_t* w1b  = (ushort_t*)d_ws;                // 4096 ush = 8192 B
    ushort_t* w2bT = w1b + CC * CC;                  // 1024 ush = 2048 B
    float* scalef  = (float*)(w2bT + 16 * CC);       // 64
    float* biasf   = scalef + CC;                    // 64
    float* b2f     = biasf + CC;                     // 9

    float* out  = (float*)d_out;
    float* kout = out + (size_t)NPIX * CC;

    hipLaunchKernelGGL(setup_kernel, dim3(20), dim3(256), 0, stream,
                       w1, b1, gamma, beta, bn_mean, bn_var, w2, b2,
                       w1b, w2bT, scalef, biasf, b2f);

    hipLaunchKernelGGL(invol_fused, dim3(NPIX / 64), dim3(256), 0, stream,
                       x, w1b, w2bT, scalef, biasf, b2f, out, kout);
}

// Round 10
// 54.900 us; speedup vs baseline: 1.9969x; 1.1237x over previous
//
#include <hip/hip_runtime.h>

typedef unsigned int uint;
typedef unsigned short ushort_t;
typedef __attribute__((ext_vector_type(8))) short short8v;   // 8 bf16 (4 VGPRs)
typedef __attribute__((ext_vector_type(4))) float f32x4;

#define BATCH 8
#define HH 128
#define WW 128
#define CC 64
#define NPIX (BATCH * HH * WW)   // 131072
#define KK 9
#define BN_EPS 1e-3f

__device__ __forceinline__ uint f2bfbits(float f) {
    uint u = __float_as_uint(f);
    return (u + 0x7fffu + ((u >> 16) & 1u)) >> 16;   // RNE
}

// ---- setup: w1 -> bf16 [d][c]; w2 -> bf16 transposed [k][d] (16 rows, pad 0); fold BN ----
__global__ void setup_kernel(const float* __restrict__ w1,
                             const float* __restrict__ b1,
                             const float* __restrict__ gamma,
                             const float* __restrict__ beta,
                             const float* __restrict__ bn_mean,
                             const float* __restrict__ bn_var,
                             const float* __restrict__ w2,
                             const float* __restrict__ b2,
                             ushort_t* __restrict__ w1b,    // [64][64] bf16: w1b[d][c] = w1[c][d]
                             ushort_t* __restrict__ w2bT,   // [16][64] bf16: w2bT[k][d] = w2[d][k]
                             float* __restrict__ scalef,    // [64]
                             float* __restrict__ biasf,     // [64]
                             float* __restrict__ b2f)       // [9]
{
    int t = blockIdx.x * blockDim.x + threadIdx.x;
    int nt = gridDim.x * blockDim.x;
    for (int idx = t; idx < CC * CC; idx += nt) {
        int d = idx >> 6, c = idx & 63;
        w1b[idx] = (ushort_t)f2bfbits(w1[c * CC + d]);
    }
    for (int idx = t; idx < 16 * CC; idx += nt) {
        int k = idx >> 6, d = idx & 63;
        w2bT[idx] = (k < KK) ? (ushort_t)f2bfbits(w2[d * KK + k]) : (ushort_t)0;
    }
    if (t < CC) {
        float s = gamma[t] * rsqrtf(bn_var[t] + BN_EPS);
        scalef[t] = s;
        biasf[t] = (b1[t] - bn_mean[t]) * s + beta[t];
    }
    if (t < KK) b2f[t] = b2[t];
}

// ---- K1: kern generation. wave = 64 px, deep-MLP MFMA, no barriers ----
__global__ __launch_bounds__(256, 2) void kern_gen(
    const float* __restrict__ x,
    const ushort_t* __restrict__ w1b,
    const ushort_t* __restrict__ w2bT,
    const float* __restrict__ scalef,
    const float* __restrict__ biasf,
    const float* __restrict__ b2f,
    float* __restrict__ kout)    // [NPIX][9]
{
    __shared__ ushort_t hL[4][64][72];   // per-wave h (bf16), 36 KB
    __shared__ float    kS[4][64 * 9];   // per-wave kern, 9 KB (packed for coalesced drain)

    const int t = threadIdx.x;
    const int w = __builtin_amdgcn_readfirstlane(t >> 6);
    const int l = t & 63;
    const int lq = l >> 4, lr = l & 15;
    int bid = blockIdx.x;
    bid = (bid & 7) * 64 + (bid >> 3);     // XCD swizzle (512 = 8*64, bijective)
    const int p0 = bid * 256 + w * 64;     // this wave's 64-pixel base

    // ---- A-tiles: 16 independent float4 loads (deep MLP), then cvt ----
    float4 xv[4][2][2];
#pragma unroll
    for (int m = 0; m < 4; ++m) {
        const float* xr = x + (size_t)(p0 + m * 16 + lr) * CC;
#pragma unroll
        for (int ks = 0; ks < 2; ++ks) {
            xv[m][ks][0] = *(const float4*)(xr + ks * 32 + lq * 8);
            xv[m][ks][1] = *(const float4*)(xr + ks * 32 + lq * 8 + 4);
        }
    }
    short8v af[4][2];
#pragma unroll
    for (int m = 0; m < 4; ++m)
#pragma unroll
        for (int ks = 0; ks < 2; ++ks) {
            union { uint4 u; short8v s; } cv;
            float4 a = xv[m][ks][0], b = xv[m][ks][1];
            cv.u.x = f2bfbits(a.x) | (f2bfbits(a.y) << 16);
            cv.u.y = f2bfbits(a.z) | (f2bfbits(a.w) << 16);
            cv.u.z = f2bfbits(b.x) | (f2bfbits(b.y) << 16);
            cv.u.w = f2bfbits(b.z) | (f2bfbits(b.w) << 16);
            af[m][ks] = cv.s;
        }

    // ---- B-frags (L1-hot after first block) ----
    short8v bf[4][2];
#pragma unroll
    for (int n = 0; n < 4; ++n)
#pragma unroll
        for (int ks = 0; ks < 2; ++ks)
            bf[n][ks] = *(const short8v*)(w1b + (n * 16 + lr) * CC + ks * 32 + lq * 8);

    // ---- GEMM1: 32 MFMA; acc[m][n] (r6-proven fragment recipe) ----
    f32x4 acc[4][4];
#pragma unroll
    for (int m = 0; m < 4; ++m)
#pragma unroll
        for (int n = 0; n < 4; ++n) acc[m][n] = (f32x4){0.f, 0.f, 0.f, 0.f};
#pragma unroll
    for (int ks = 0; ks < 2; ++ks)
#pragma unroll
        for (int n = 0; n < 4; ++n)
#pragma unroll
            for (int m = 0; m < 4; ++m)
                acc[m][n] = __builtin_amdgcn_mfma_f32_16x16x32_bf16(af[m][ks], bf[n][ks], acc[m][n], 0, 0, 0);

    // ---- epilogue: BN+ReLU -> bf16 -> hL (C layout: row=px=m*16+lq*4+r, col=d=n*16+lr) ----
    float sv[4], bv[4];
#pragma unroll
    for (int n = 0; n < 4; ++n) { sv[n] = scalef[n * 16 + lr]; bv[n] = biasf[n * 16 + lr]; }
#pragma unroll
    for (int m = 0; m < 4; ++m)
#pragma unroll
        for (int n = 0; n < 4; ++n)
#pragma unroll
            for (int r = 0; r < 4; ++r) {
                float hv = fmaxf(fmaf(acc[m][n][r], sv[n], bv[n]), 0.f);
                hL[w][m * 16 + lq * 4 + r][n * 16 + lr] = (ushort_t)f2bfbits(hv);
            }
    // same-wave LDS handoff (compiler lgkmcnt; r9-proven)

    // ---- GEMM2: kern = h @ w2 (M=64 px in 4 tiles, N=16 pad, K=64); r9-proven recipe ----
    f32x4 acc2[4];
#pragma unroll
    for (int m2 = 0; m2 < 4; ++m2) acc2[m2] = (f32x4){0.f, 0.f, 0.f, 0.f};
#pragma unroll
    for (int ks = 0; ks < 2; ++ks) {
        short8v b2v = *(const short8v*)(w2bT + lr * CC + ks * 32 + lq * 8);
#pragma unroll
        for (int m2 = 0; m2 < 4; ++m2) {
            short8v a2 = *(const short8v*)(&hL[w][m2 * 16 + lr][ks * 32 + lq * 8]);
            acc2[m2] = __builtin_amdgcn_mfma_f32_16x16x32_bf16(a2, b2v, acc2[m2], 0, 0, 0);
        }
    }
    // C2: lane holds kern[px=m2*16+lq*4+r][k=lr] (lr<9 valid) -> packed kS
    if (lr < KK) {
        const float bk = b2f[lr];
#pragma unroll
        for (int m2 = 0; m2 < 4; ++m2)
#pragma unroll
            for (int r = 0; r < 4; ++r)
                kS[w][(m2 * 16 + lq * 4 + r) * KK + lr] = acc2[m2][r] + bk;
    }
    // same-wave handoff, then coalesced drain: 144 contiguous float4 per wave
    {
        float* kbase = kout + (size_t)p0 * KK;
#pragma unroll
        for (int rep = 0; rep < 3; ++rep) {
            int idx = rep * 64 + l;
            if (idx < 144) {
                f32x4 v = *(f32x4*)(&kS[w][idx * 4]);
                *(f32x4*)(kbase + idx * 4) = v;
            }
        }
    }
}

// ---- K2: involution (r5-proven). thread = (pixel, 16-ch quarter). plain stores ----
__global__ __launch_bounds__(256) void invol2(
    const float* __restrict__ x,
    const float* __restrict__ kern_in,   // [NPIX][9]
    float* __restrict__ out)             // [NPIX][64]
{
    int bid = blockIdx.x;
    bid = (bid & 7) * 256 + (bid >> 3);  // XCD swizzle (2048 = 8*256, bijective)
    int T = bid * 256 + threadIdx.x;
    int p = T >> 2;
    int c0 = (T & 3) * 16;
    int b = p >> 14;
    int i = (p >> 7) & 127;
    int j = p & 127;

    float kern[KK];
    const float* kr = kern_in + (size_t)p * KK;
#pragma unroll
    for (int k = 0; k < KK; ++k) kern[k] = kr[k];

    float acc[16];
#pragma unroll
    for (int e = 0; e < 16; ++e) acc[e] = 0.f;

#pragma unroll
    for (int tap = 0; tap < KK; ++tap) {
        const int di = tap / 3 - 1, dj = tap % 3 - 1;
        int ii = i + di, jj = j + dj;
        bool valid = (ii >= 0) && (ii < HH) && (jj >= 0) && (jj < WW);
        float kv = valid ? kern[tap] : 0.f;
        int iic = min(max(ii, 0), HH - 1);
        int jjc = min(max(jj, 0), WW - 1);
        const float4* np = (const float4*)(x + (((size_t)b * HH + iic) * WW + jjc) * CC + c0);
#pragma unroll
        for (int f = 0; f < 4; ++f) {
            float4 v = np[f];
            acc[f * 4 + 0] = fmaf(kv, v.x, acc[f * 4 + 0]);
            acc[f * 4 + 1] = fmaf(kv, v.y, acc[f * 4 + 1]);
            acc[f * 4 + 2] = fmaf(kv, v.z, acc[f * 4 + 2]);
            acc[f * 4 + 3] = fmaf(kv, v.w, acc[f * 4 + 3]);
        }
    }

    float4* op = (float4*)(out + (size_t)p * CC + c0);
#pragma unroll
    for (int f = 0; f < 4; ++f)
        op[f] = make_float4(acc[f * 4 + 0], acc[f * 4 + 1], acc[f * 4 + 2], acc[f * 4 + 3]);
}

extern "C" void kernel_launch(void* const* d_in, const int* in_sizes, int n_in,
                              void* d_out, int out_size, void* d_ws, size_t ws_size,
                              hipStream_t stream) {
    const float* x       = (const float*)d_in[0];
    const float* w1      = (const float*)d_in[1];
    const float* b1      = (const float*)d_in[2];
    const float* gamma   = (const float*)d_in[3];
    const float* beta    = (const float*)d_in[4];
    const float* bn_mean = (const float*)d_in[5];
    const float* bn_var  = (const float*)d_in[6];
    const float* w2      = (const float*)d_in[7];
    const float* b2      = (const float*)d_in[8];

    ushort_t* w1b  = (ushort_t*)d_ws;                // 4096 ush = 8192 B
    ushort_t* w2bT = w1b + CC * CC;                  // 1024 ush = 2048 B
    float* scalef  = (float*)(w2bT + 16 * CC);       // 64
    float* biasf   = scalef + CC;                    // 64
    float* b2f     = biasf + CC;                     // 9

    float* out  = (float*)d_out;
    float* kout = out + (size_t)NPIX * CC;

    hipLaunchKernelGGL(setup_kernel, dim3(20), dim3(256), 0, stream,
                       w1, b1, gamma, beta, bn_mean, bn_var, w2, b2,
                       w1b, w2bT, scalef, biasf, b2f);

    hipLaunchKernelGGL(kern_gen, dim3(NPIX / 256), dim3(256), 0, stream,
                       x, w1b, w2bT, scalef, biasf, b2f, kout);

    hipLaunchKernelGGL(invol2, dim3(NPIX * 4 / 256), dim3(256), 0, stream,
                       x, kout, out);
}